// Round 10
// baseline (1667.020 us; speedup 1.0000x reference)
//
#include <hip/hip_runtime.h>

// 2-layer LSTM (B=256, T=512, D=64, H=256) + FC(256->4).
// 32 groups x 8 blocks; blocks 0-3: layer 0 quadrant q, 4-7: layer 1 quadrant q.
// Systolic skew: iter s computes h0(s) on L0, h1(s-1) on L1.
// Round-10: 256-thread blocks, 4 waves; wave m owns ALL 4 gates for h-indices
// [16m,16m+16) with full K -> activation fully in-register from C0..C3[reg]
// (C layout col=lane&15,row=(lane>>4)*4+reg). No part2 reduction, ONE barrier
// per step. A-fragments: 64 named f16x8 SSA (256 VGPR); launch_bounds(256,1).
// Exchange: r8's epoch-packet protocol (u64 {epoch32|2xf16}, ring-4, relaxed
// agent atomics, slack-2 cflag guard). Own-quadrant h -> own sB directly.
// sB double-buffered by step parity; staging writes par^1 while MFMA reads par.

#define TT 512
#define HH 256
#define DD 64

typedef __attribute__((ext_vector_type(2))) _Float16 h2t;
typedef __attribute__((ext_vector_type(8))) _Float16 f16x8;
typedef __attribute__((ext_vector_type(4))) float f32x4;
typedef unsigned long long u64;
typedef unsigned u32;

__device__ __forceinline__ u32 pkh(float x, float y) {
    h2t h; h.x = (_Float16)x; h.y = (_Float16)y;
    return __builtin_bit_cast(u32, h);
}
__device__ __forceinline__ float sigf(float x) { return 1.f / (1.f + __expf(-x)); }
__device__ __forceinline__ float tanhf_(float x) {
    float e = __expf(2.f * x);
    return 1.f - 2.f / (e + 1.f);   // safe at +/-inf
}
__device__ __forceinline__ f16x8 ld8(const float* p) {
    float4 u = ((const float4*)p)[0];
    float4 v = ((const float4*)p)[1];
    f16x8 r = {(_Float16)u.x, (_Float16)u.y, (_Float16)u.z, (_Float16)u.w,
               (_Float16)v.x, (_Float16)v.y, (_Float16)v.z, (_Float16)v.w};
    return r;
}
__device__ __forceinline__ u32 ld32(const u32* p) {
    return __hip_atomic_load(p, __ATOMIC_RELAXED, __HIP_MEMORY_SCOPE_AGENT);
}
__device__ __forceinline__ void st32(u32* p, u32 v) {
    __hip_atomic_store(p, v, __ATOMIC_RELAXED, __HIP_MEMORY_SCOPE_AGENT);
}
__device__ __forceinline__ u64 ld64(const u64* p) {
    return __hip_atomic_load(p, __ATOMIC_RELAXED, __HIP_MEMORY_SCOPE_AGENT);
}
__device__ __forceinline__ void st64(u64* p, u64 v) {
    __hip_atomic_store(p, v, __ATOMIC_RELAXED, __HIP_MEMORY_SCOPE_AGENT);
}

__global__ __launch_bounds__(256, 1) void lstm_persist(
    const float* __restrict__ x,
    const float* __restrict__ Wih0, const float* __restrict__ Whh0,
    const float* __restrict__ bih0, const float* __restrict__ bhh0,
    const float* __restrict__ Wih1, const float* __restrict__ Whh1,
    const float* __restrict__ bih1, const float* __restrict__ bhh1,
    const float* __restrict__ fcW, const float* __restrict__ fcb,
    float* __restrict__ out,
    u64* h0ring, u64* h1ring, u32* cflagsA)
{
    // sB: 2 parities x 64 chunks x 144 halves (288B chunk stride, bank-balanced)
    __shared__ __align__(16) _Float16 sB[18432];   // 36 KB
    __shared__ __align__(16) float sBias[4][64];   // 1 KB

    const int tid  = threadIdx.x;                  // 0..255
    const int g    = blockIdx.x & 31;
    const int role = blockIdx.x >> 5;              // 0..7
    const bool isL1 = role >= 4;
    const int q = role & 3;
    const int batch0 = g * 8;
    u64* ring0 = h0ring + (size_t)g * 4096;        // [slot4][q4][b8][hp32] u64
    u64* ring1 = h1ring + (size_t)g * 4096;
    u32* cflag = cflagsA + (size_t)g * 16;

    const int lane = tid & 63, w = tid >> 6;       // wave 0..3: h-idx [16w,16w+16)
    const int bcol = lane & 15;                    // B col = batch (8..15 pad)
    const int p_   = lane >> 4;                    // quarter: rows 4p..4p+3
    const int koff = p_ * 8;

    // ---- A-fragment rows (row = lane&15 within tile) ----
    const int rb = 64 * q + 16 * w + bcol;
    const int R0 = rb, R1 = 256 + rb, R2 = 512 + rb, R3 = 768 + rb;

#define DECLG(gg) f16x8 A##gg##_0={},A##gg##_1={},A##gg##_2={},A##gg##_3={}, \
    A##gg##_4={},A##gg##_5={},A##gg##_6={},A##gg##_7={},A##gg##_8={},        \
    A##gg##_9={},A##gg##_10={},A##gg##_11={},A##gg##_12={},A##gg##_13={},    \
    A##gg##_14={},A##gg##_15={};
    DECLG(0) DECLG(1) DECLG(2) DECLG(3)
#undef DECLG

    if (isL1) {
        // K = [h0: 0..255 | h1: 256..511]; kt 0..7 from Wih1, 8..15 from Whh1
#define L1G(gg) \
    A##gg##_0 =ld8(Wih1+(size_t)R##gg*256+  0+koff); A##gg##_1 =ld8(Wih1+(size_t)R##gg*256+ 32+koff); \
    A##gg##_2 =ld8(Wih1+(size_t)R##gg*256+ 64+koff); A##gg##_3 =ld8(Wih1+(size_t)R##gg*256+ 96+koff); \
    A##gg##_4 =ld8(Wih1+(size_t)R##gg*256+128+koff); A##gg##_5 =ld8(Wih1+(size_t)R##gg*256+160+koff); \
    A##gg##_6 =ld8(Wih1+(size_t)R##gg*256+192+koff); A##gg##_7 =ld8(Wih1+(size_t)R##gg*256+224+koff); \
    A##gg##_8 =ld8(Whh1+(size_t)R##gg*256+  0+koff); A##gg##_9 =ld8(Whh1+(size_t)R##gg*256+ 32+koff); \
    A##gg##_10=ld8(Whh1+(size_t)R##gg*256+ 64+koff); A##gg##_11=ld8(Whh1+(size_t)R##gg*256+ 96+koff); \
    A##gg##_12=ld8(Whh1+(size_t)R##gg*256+128+koff); A##gg##_13=ld8(Whh1+(size_t)R##gg*256+160+koff); \
    A##gg##_14=ld8(Whh1+(size_t)R##gg*256+192+koff); A##gg##_15=ld8(Whh1+(size_t)R##gg*256+224+koff);
        L1G(0) L1G(1) L1G(2) L1G(3)
#undef L1G
    } else {
        // K = [x: 0..63 | h0: 64..319]; kt 0..1 from Wih0, 2..9 from Whh0
#define L0G(gg) \
    A##gg##_0=ld8(Wih0+(size_t)R##gg*64+koff); A##gg##_1=ld8(Wih0+(size_t)R##gg*64+32+koff); \
    A##gg##_2=ld8(Whh0+(size_t)R##gg*256+  0+koff); A##gg##_3=ld8(Whh0+(size_t)R##gg*256+ 32+koff); \
    A##gg##_4=ld8(Whh0+(size_t)R##gg*256+ 64+koff); A##gg##_5=ld8(Whh0+(size_t)R##gg*256+ 96+koff); \
    A##gg##_6=ld8(Whh0+(size_t)R##gg*256+128+koff); A##gg##_7=ld8(Whh0+(size_t)R##gg*256+160+koff); \
    A##gg##_8=ld8(Whh0+(size_t)R##gg*256+192+koff); A##gg##_9=ld8(Whh0+(size_t)R##gg*256+224+koff);
        L0G(0) L0G(1) L0G(2) L0G(3)
#undef L0G
    }

    // ---- biases for local quadrant into LDS (act reads broadcast float4) ----
    {
        int g_ = tid >> 6, i_ = tid & 63;
        const float* bA = isL1 ? bih1 : bih0;
        const float* bB = isL1 ? bhh1 : bhh0;
        sBias[g_][i_] = bA[g_ * 256 + 64 * q + i_] + bB[g_ * 256 + 64 * q + i_];
    }
    // ---- zero both sB parities (pad rows 8-15 + h(-1)=0 initial state) ----
    for (int i = tid; i < 9216; i += 256) ((u32*)sB)[i] = 0;
    __syncthreads();
    // prologue: stage x(0) into parity 0 (L0 only)
    if (!isL1 && tid < 128) {
        int j = tid >> 4, c = tid & 15;
        float4 v = ((const float4*)(x + (size_t)(batch0 + j) * TT * DD))[c];
        int bi = (c >> 1) * 72 + j * 4 + 2 * (c & 1);
        ((u32*)sB)[bi] = pkh(v.x, v.y); ((u32*)sB)[bi + 1] = pkh(v.z, v.w);
    }

    float c0_ = 0.f, c1_ = 0.f, c2_ = 0.f, c3_ = 0.f;   // c-state: 4 rows/lane

    for (int s = 0; s <= TT; ++s) {
        const int par = s & 1;
        __syncthreads();   // staging(s) complete; sB[par] ready block-wide
        if (tid == 0) st32(&cflag[role], (u32)(s + 1));

        const bool act_ = isL1 ? (s >= 1) : (s < TT);
        const int  snx  = s + 1;
        const bool stg0 = (!isL1) && (snx < TT);
        const bool stg1 = isL1 && (snx <= TT);

        // guard-flag pre-load (overlaps MFMA) + x prefetch (no peer dependency)
        u32 cpre = 0u;
        if (act_ && lane < 8) cpre = ld32(&cflag[lane]);
        float4 xr;
        const bool doX = stg0 && (tid < 128);
        if (doX) {
            int j = tid >> 4, c = tid & 15;
            xr = ((const float4*)(x + ((size_t)(batch0 + j) * TT + snx) * DD))[c];
        }

        if (act_) {
            const _Float16* sBp = sB + par * 9216;
            f32x4 C0 = {0,0,0,0}, C1 = {0,0,0,0}, C2 = {0,0,0,0}, C3 = {0,0,0,0};
#define MST(kt) { const f16x8 Bf = *(const f16x8*)(sBp + ((kt)*4 + p_)*144 + bcol*8); \
            C0 = __builtin_amdgcn_mfma_f32_16x16x32_f16(A0_##kt, Bf, C0, 0,0,0); \
            C1 = __builtin_amdgcn_mfma_f32_16x16x32_f16(A1_##kt, Bf, C1, 0,0,0); \
            C2 = __builtin_amdgcn_mfma_f32_16x16x32_f16(A2_##kt, Bf, C2, 0,0,0); \
            C3 = __builtin_amdgcn_mfma_f32_16x16x32_f16(A3_##kt, Bf, C3, 0,0,0); }
            if (isL1) {
                MST(0) MST(1) MST(2) MST(3) MST(4) MST(5) MST(6) MST(7)
                MST(8) MST(9) MST(10) MST(11) MST(12) MST(13) MST(14) MST(15)
            } else {
                MST(0) MST(1) MST(2) MST(3) MST(4) MST(5) MST(6) MST(7) MST(8) MST(9)
            }
#undef MST
            if (bcol < 8) {
                // in-register activation: reg r of C0..C3 = i,f,g,o of h-idx 16w+4p+r
                const f32x4 bi0 = *(const f32x4*)&sBias[0][16 * w + 4 * p_];
                const f32x4 bi1 = *(const f32x4*)&sBias[1][16 * w + 4 * p_];
                const f32x4 bi2 = *(const f32x4*)&sBias[2][16 * w + 4 * p_];
                const f32x4 bi3 = *(const f32x4*)&sBias[3][16 * w + 4 * p_];
                float h0v, h1v, h2v, h3v;
#define ACTR(r, cr) { float fi = sigf(C0[r] + bi0[r]), ff = sigf(C1[r] + bi1[r]); \
                float fg = tanhf_(C2[r] + bi2[r]), fo = sigf(C3[r] + bi3[r]);     \
                cr = ff * cr + fi * fg; h##r##v = fo * tanhf_(cr); }
                ACTR(0, c0_) ACTR(1, c1_) ACTR(2, c2_) ACTR(3, c3_)
#undef ACTR
                u32 lo = pkh(h0v, h1v), hi = pkh(h2v, h3v);

                // own-quadrant direct into sB[par^1] (no ring RTT)
                const int idx0 = 64 * q + 16 * w + 4 * p_;
                u32* dstP = (u32*)sB + (par ^ 1) * 4608;
                const int sl = ((isL1 ? 32 : 8) + (idx0 >> 3)) * 72 + bcol * 4
                               + ((idx0 & 7) >> 1);
                dstP[sl] = lo; dstP[sl + 1] = hi;

                // ring-overwrite guard: all 8 blocks staged step s-2 (slack 2)
                const int tgt = s - 2;
                while (!__all(lane >= 8 || (int)cpre >= tgt)) {
                    __builtin_amdgcn_s_sleep(1);
                    if (lane < 8) cpre = ld32(&cflag[lane]);
                }
                // ring store: packets {epoch s+1 | 2 x f16}, hp = 8w + 2p (+1)
                const u64 ep = (u64)(u32)(s + 1) << 32;
                u64* rdst = (isL1 ? ring1 + (size_t)((s - 1) & 3) * 1024
                                  : ring0 + (size_t)(s & 3) * 1024)
                            + q * 256 + bcol * 32 + 8 * w + 2 * p_;
                st64(rdst, ep | (u64)lo);
                st64(rdst + 1, ep | (u64)hi);
            }
        }

        // ---- stage step s+1 into sB[par^1]; thread tid = (b = tid>>5, hp = tid&31)
        if (stg1) {
            const int i0 = (q + 1) & 3, i1 = (q + 2) & 3, i2 = (q + 3) & 3;
            const u64* a0 = ring0 + (size_t)((snx - 1) & 3) * 1024 + tid;
            const u64* a1 = ring1 + (size_t)((snx + 2) & 3) * 1024 + tid;
            u64 v0 = ld64(a0),          v1 = ld64(a0 + 256);
            u64 v2 = ld64(a0 + 512),    v3 = ld64(a0 + 768);
            u64 v4 = ld64(a1 + i0*256), v5 = ld64(a1 + i1*256), v6 = ld64(a1 + i2*256);
            const u32 e0 = (u32)snx, e1 = (snx >= 2) ? (u32)snx : 0u;
            for (;;) {
                bool k0 = ((u32)(v0 >> 32) == e0), k1 = ((u32)(v1 >> 32) == e0),
                     k2 = ((u32)(v2 >> 32) == e0), k3 = ((u32)(v3 >> 32) == e0),
                     k4 = ((u32)(v4 >> 32) == e1), k5 = ((u32)(v5 >> 32) == e1),
                     k6 = ((u32)(v6 >> 32) == e1);
                if (k0 & k1 & k2 & k3 & k4 & k5 & k6) break;
                if (!k0) v0 = ld64(a0);          if (!k1) v1 = ld64(a0 + 256);
                if (!k2) v2 = ld64(a0 + 512);    if (!k3) v3 = ld64(a0 + 768);
                if (!k4) v4 = ld64(a1 + i0*256); if (!k5) v5 = ld64(a1 + i1*256);
                if (!k6) v6 = ld64(a1 + i2*256);
            }
            u32* d = (u32*)sB + (par ^ 1) * 4608;
            const int b = tid >> 5, hp = tid & 31;
            const int wof = (hp >> 2) * 72 + b * 4 + (hp & 3);
            d[wof]          = (u32)v0;            // h0 cbase 0, quadrant i
            d[wof + 576]    = (u32)v1;
            d[wof + 1152]   = (u32)v2;
            d[wof + 1728]   = (u32)v3;
            d[wof + 2304 + 576 * i0] = (u32)v4;   // h1 cbase 32, skip own q
            d[wof + 2304 + 576 * i1] = (u32)v5;
            d[wof + 2304 + 576 * i2] = (u32)v6;
        } else if (stg0) {
            const int i0 = (q + 1) & 3, i1 = (q + 2) & 3, i2 = (q + 3) & 3;
            const u64* a0 = ring0 + (size_t)((snx - 1) & 3) * 1024 + tid;
            u64 v0 = ld64(a0 + i0*256), v1 = ld64(a0 + i1*256), v2 = ld64(a0 + i2*256);
            const u32 e0 = (u32)snx;
            for (;;) {
                bool k0 = ((u32)(v0 >> 32) == e0), k1 = ((u32)(v1 >> 32) == e0),
                     k2 = ((u32)(v2 >> 32) == e0);
                if (k0 & k1 & k2) break;
                if (!k0) v0 = ld64(a0 + i0*256);
                if (!k1) v1 = ld64(a0 + i1*256);
                if (!k2) v2 = ld64(a0 + i2*256);
            }
            u32* d = (u32*)sB + (par ^ 1) * 4608;
            const int b = tid >> 5, hp = tid & 31;
            const int wof = (hp >> 2) * 72 + b * 4 + (hp & 3);
            d[wof + 576 + 576 * i0] = (u32)v0;    // h0 cbase 8, skip own q
            d[wof + 576 + 576 * i1] = (u32)v1;
            d[wof + 576 + 576 * i2] = (u32)v2;
            if (doX) {
                int j = tid >> 4, c = tid & 15;
                int bi = (c >> 1) * 72 + j * 4 + 2 * (c & 1);
                d[bi] = pkh(xr.x, xr.y); d[bi + 1] = pkh(xr.z, xr.w);
            }
        }
    }

    // ---- final FC on h1(TT-1): ring1 slot 3, epoch TT+1; role-4 block ----
    if (role == 4) {
        __syncthreads();   // all waves done reading sB before reuse
        const u32 ef = (u32)(TT + 1);
        const u64* a = ring1 + 3 * 1024 + tid;
        u64 w0 = ld64(a), w1 = ld64(a + 256), w2 = ld64(a + 512), w3 = ld64(a + 768);
        for (;;) {
            bool k0 = ((u32)(w0 >> 32) == ef), k1 = ((u32)(w1 >> 32) == ef),
                 k2 = ((u32)(w2 >> 32) == ef), k3 = ((u32)(w3 >> 32) == ef);
            if (k0 & k1 & k2 & k3) break;
            if (!k0) w0 = ld64(a);        if (!k1) w1 = ld64(a + 256);
            if (!k2) w2 = ld64(a + 512);  if (!k3) w3 = ld64(a + 768);
        }
        {
            const int b = tid >> 5, hp = tid & 31;   // flat halves sB[b*256 + 64i + 2hp]
            u32* d = (u32*)sB;
            d[b * 128 + hp]      = (u32)w0;
            d[b * 128 + 32 + hp] = (u32)w1;
            d[b * 128 + 64 + hp] = (u32)w2;
            d[b * 128 + 96 + hp] = (u32)w3;
        }
        __syncthreads();
        const int j = tid >> 5, l2 = tid & 31;
        const int o = l2 >> 3, kk = l2 & 7;
        float ssum = 0.f;
#pragma unroll
        for (int m = 0; m < 32; ++m) {
            int k = kk * 32 + m;
            ssum += (float)sB[j * 256 + k] * fcW[o * HH + k];
        }
        ssum += __shfl_down(ssum, 4);
        ssum += __shfl_down(ssum, 2);
        ssum += __shfl_down(ssum, 1);
        if (kk == 0) out[(batch0 + j) * 4 + o] = ssum + fcb[o];
    }
}

extern "C" void kernel_launch(void* const* d_in, const int* in_sizes, int n_in,
                              void* d_out, int out_size, void* d_ws, size_t ws_size,
                              hipStream_t stream)
{
    (void)in_sizes; (void)n_in; (void)out_size; (void)ws_size;
    const float* x    = (const float*)d_in[0];
    const float* Wih0 = (const float*)d_in[1];
    const float* Whh0 = (const float*)d_in[2];
    const float* bih0 = (const float*)d_in[3];
    const float* bhh0 = (const float*)d_in[4];
    const float* Wih1 = (const float*)d_in[5];
    const float* Whh1 = (const float*)d_in[6];
    const float* bih1 = (const float*)d_in[7];
    const float* bhh1 = (const float*)d_in[8];
    const float* fcW  = (const float*)d_in[9];
    const float* fcb  = (const float*)d_in[10];
    float* out = (float*)d_out;

    // ws: h0ring 1MB (32 grp x 4 slot x 1024 u64) | h1ring 1MB | cflags 2KB
    u64* h0ring = (u64*)d_ws;
    u64* h1ring = (u64*)((char*)d_ws + 1048576);
    u32* cflags = (u32*)((char*)d_ws + 2097152);

    hipMemsetAsync(d_ws, 0, 2097152 + 2048, stream);   // epoch 0 == h(-1)=0

    lstm_persist<<<dim3(256), dim3(256), 0, stream>>>(
        x, Wih0, Whh0, bih0, bhh0, Wih1, Whh1, bih1, bhh1, fcW, fcb, out,
        h0ring, h1ring, cflags);
}

// Round 12
// 1318.699 us; speedup vs baseline: 1.2641x; 1.2641x over previous
//
#include <hip/hip_runtime.h>

// 2-layer LSTM (B=256, T=512, D=64, H=256) + FC(256->4).
// 32 groups x 8 blocks; blocks 0-3: layer 0 quadrant q, 4-7: layer 1 quadrant q.
// Systolic skew: iter s computes h0(s) on L0, h1(s-1) on L1. r8 protocol:
// u64 packets {epoch32|2xf16} via relaxed agent-scope atomics (L3 coherence
// point -- the only verified-correct cross-block path), ring-4 slots,
// slack-2 cflag guard, 2 barriers/step.
// Round-12 (recovery from r11 timeout -- sc0 fast path removed entirely):
//   * staging loads all issued back-to-back + ONE joint retry loop
//     (r8 serialized h0-retry -> h1-issue -> x-issue: 2-4 dependent L3 RTTs)
//   * x(s+1) prefetched before MFMA (plain cached load, protocol-free)

#define TT 512
#define HH 256
#define DD 64

typedef __attribute__((ext_vector_type(2))) _Float16 h2t;
typedef __attribute__((ext_vector_type(8))) _Float16 f16x8;
typedef __attribute__((ext_vector_type(4))) float f32x4;
typedef unsigned long long u64;
typedef unsigned u32;

__device__ __forceinline__ u32 pkh(float x, float y) {
    h2t h; h.x = (_Float16)x; h.y = (_Float16)y;
    return __builtin_bit_cast(u32, h);
}
__device__ __forceinline__ float sigf(float x) { return 1.f / (1.f + __expf(-x)); }
__device__ __forceinline__ float tanhf_(float x) {
    float e = __expf(2.f * x);
    return 1.f - 2.f / (e + 1.f);   // safe at +/-inf
}
__device__ __forceinline__ f16x8 ld8(const float* p) {
    float4 u = ((const float4*)p)[0];
    float4 v = ((const float4*)p)[1];
    f16x8 r = {(_Float16)u.x, (_Float16)u.y, (_Float16)u.z, (_Float16)u.w,
               (_Float16)v.x, (_Float16)v.y, (_Float16)v.z, (_Float16)v.w};
    return r;
}
__device__ __forceinline__ u32 ld32(const u32* p) {
    return __hip_atomic_load(p, __ATOMIC_RELAXED, __HIP_MEMORY_SCOPE_AGENT);
}
__device__ __forceinline__ void st32(u32* p, u32 v) {
    __hip_atomic_store(p, v, __ATOMIC_RELAXED, __HIP_MEMORY_SCOPE_AGENT);
}
__device__ __forceinline__ u64 ld64(const u64* p) {
    return __hip_atomic_load(p, __ATOMIC_RELAXED, __HIP_MEMORY_SCOPE_AGENT);
}
__device__ __forceinline__ void st64(u64* p, u64 v) {
    __hip_atomic_store(p, v, __ATOMIC_RELAXED, __HIP_MEMORY_SCOPE_AGENT);
}

__global__ __launch_bounds__(512, 2) void lstm_persist(
    const float* __restrict__ x,
    const float* __restrict__ Wih0, const float* __restrict__ Whh0,
    const float* __restrict__ bih0, const float* __restrict__ bhh0,
    const float* __restrict__ Wih1, const float* __restrict__ Whh1,
    const float* __restrict__ bih1, const float* __restrict__ bhh1,
    const float* __restrict__ fcW, const float* __restrict__ fcb,
    float* __restrict__ out,
    u64* h0ring, u64* h1ring, u32* cflagsA)
{
    __shared__ __align__(16) _Float16 sB[9216];        // 64 chunks x 144 halves
    __shared__ __align__(16) float part2[2][8][276];   // k-split partials

    const int tid  = threadIdx.x;
    const int g    = blockIdx.x & 31;
    const int role = blockIdx.x >> 5;
    const bool isL1 = role >= 4;
    const int q = role & 3;
    const int batch0 = g * 8;
    u64* ring0 = h0ring + (size_t)g * 4096;   // [slot4][q4][j8][hp32]
    u64* ring1 = h1ring + (size_t)g * 4096;
    u32* cflag = cflagsA + (size_t)g * 16;

    const int lane = tid & 63, w = tid >> 6;
    const int mw = w & 3, kh = w >> 2;
    const int bcol = lane & 15, kc = lane >> 4;

    // ---- A-fragment rows: wave mw owns gate mw; tiles ti=0..3 ----
    const int R0 = mw * 256 + 64 * q + (lane & 15);
    const int R1 = R0 + 16, R2 = R0 + 32, R3 = R0 + 48;

#define DECL_TI(ti) f16x8 A##ti##_0={},A##ti##_1={},A##ti##_2={},A##ti##_3={}, \
                          A##ti##_4={},A##ti##_5={},A##ti##_6={},A##ti##_7={};
    DECL_TI(0) DECL_TI(1) DECL_TI(2) DECL_TI(3)
#undef DECL_TI

    if (isL1) {
#define LDA1(ti,j) { int k_ = (kh*8+(j))*32 + kc*8;                          \
        A##ti##_##j = ld8(k_ < 256 ? Wih1 + (size_t)R##ti*256 + k_           \
                                   : Whh1 + (size_t)R##ti*256 + (k_-256)); }
#define LDA1T(ti) LDA1(ti,0) LDA1(ti,1) LDA1(ti,2) LDA1(ti,3) \
                  LDA1(ti,4) LDA1(ti,5) LDA1(ti,6) LDA1(ti,7)
        LDA1T(0) LDA1T(1) LDA1T(2) LDA1T(3)
#undef LDA1T
#undef LDA1
    } else {
#define LDA0(ti,j) { int k_ = (kh*5+(j))*32 + kc*8;                          \
        A##ti##_##j = ld8(k_ < 64 ? Wih0 + (size_t)R##ti*64 + k_             \
                                  : Whh0 + (size_t)R##ti*256 + (k_-64)); }
#define LDA0T(ti) LDA0(ti,0) LDA0(ti,1) LDA0(ti,2) LDA0(ti,3) LDA0(ti,4)
        LDA0T(0) LDA0T(1) LDA0T(2) LDA0T(3)
#undef LDA0T
#undef LDA0
    }

    // ---- activation duty: thread (lane = h-idx in quadrant, w = batch) ----
    const float* bA = isL1 ? bih1 : bih0;
    const float* bB = isL1 ? bhh1 : bhh0;
    const float bz0 = bA[      64*q + lane] + bB[      64*q + lane];
    const float bz1 = bA[256 + 64*q + lane] + bB[256 + 64*q + lane];
    const float bz2 = bA[512 + 64*q + lane] + bB[512 + 64*q + lane];
    const float bz3 = bA[768 + 64*q + lane] + bB[768 + 64*q + lane];
    float cst = 0.f;

    u32* const sBu = (u32*)sB;
    for (int i = tid; i < 4608; i += 512) sBu[i] = 0;   // incl. pad rows 8-15
    __syncthreads();   // zero-fill complete before x(0) staging

    // prologue: h(-1)=0 already in zeroed sB; stage only x(0)
    if (!isL1 && tid >= 256 && tid < 384) {
        int t2 = tid - 256, j = t2 >> 4, c = t2 & 15;
        float4 v = ((const float4*)(x + ((size_t)(batch0 + j) * TT) * DD))[c];
        int bidx = (c >> 1) * 72 + j * 4 + 2 * (c & 1);
        sBu[bidx]     = pkh(v.x, v.y);
        sBu[bidx + 1] = pkh(v.z, v.w);
    }

    for (int s = 0; s <= TT; ++s) {
        __syncthreads();   // staging for step s complete block-wide
        if (tid == 0) st32(&cflag[role], (u32)(s + 1));

        const bool act_ = isL1 ? (s >= 1) : (s < TT);
        const int  snx  = s + 1;
        const bool stg0 = (!isL1) && (snx < TT);
        const bool stg1 = isL1 && (snx <= TT);

        // guard-flag preload (hidden under MFMA) + x prefetch (plain cached)
        u32 cpre = 0u;
        if (act_ && lane < 8) cpre = ld32(&cflag[lane]);
        float4 xr;
        const bool doX = stg0 && (tid >= 256) && (tid < 384);
        if (doX) {
            int t2 = tid - 256, j = t2 >> 4, c = t2 & 15;
            xr = ((const float4*)(x + ((size_t)(batch0 + j) * TT + snx) * DD))[c];
        }

        // ---- MFMA: G = W . Hcat ----
        if (act_) {
            f32x4 C0 = {0,0,0,0}, C1 = {0,0,0,0}, C2 = {0,0,0,0}, C3 = {0,0,0,0};
#define MST(j, ktb) { const f16x8 Bf = *(const f16x8*)(sB + (((ktb)+(j))*4 + kc)*144 + bcol*8); \
            C0 = __builtin_amdgcn_mfma_f32_16x16x32_f16(A0_##j, Bf, C0, 0,0,0); \
            C1 = __builtin_amdgcn_mfma_f32_16x16x32_f16(A1_##j, Bf, C1, 0,0,0); \
            C2 = __builtin_amdgcn_mfma_f32_16x16x32_f16(A2_##j, Bf, C2, 0,0,0); \
            C3 = __builtin_amdgcn_mfma_f32_16x16x32_f16(A3_##j, Bf, C3, 0,0,0); }
            if (isL1) {
                const int ktb = kh * 8;
                MST(0,ktb) MST(1,ktb) MST(2,ktb) MST(3,ktb)
                MST(4,ktb) MST(5,ktb) MST(6,ktb) MST(7,ktb)
            } else {
                const int ktb = kh * 5;
                MST(0,ktb) MST(1,ktb) MST(2,ktb) MST(3,ktb) MST(4,ktb)
            }
#undef MST
            if (bcol < 8) {
                *(f32x4*)&part2[kh][bcol][mw*64 +  0 + kc*4] = C0;
                *(f32x4*)&part2[kh][bcol][mw*64 + 16 + kc*4] = C1;
                *(f32x4*)&part2[kh][bcol][mw*64 + 32 + kc*4] = C2;
                *(f32x4*)&part2[kh][bcol][mw*64 + 48 + kc*4] = C3;
            }
        }
        __syncthreads();   // part2 ready; all sB reads of step s done

        // ---- activation; ring store ----
        if (act_) {
            float s0 = part2[0][w][      lane] + part2[1][w][      lane] + bz0;
            float s1 = part2[0][w][ 64 + lane] + part2[1][w][ 64 + lane] + bz1;
            float s2 = part2[0][w][128 + lane] + part2[1][w][128 + lane] + bz2;
            float s3 = part2[0][w][192 + lane] + part2[1][w][192 + lane] + bz3;
            float fi = sigf(s0), ff = sigf(s1), fg = tanhf_(s2), fo = sigf(s3);
            cst = ff * cst + fi * fg;
            float h = fo * tanhf_(cst);
            float hn = __shfl_down(h, 1);
            u32 hw = pkh(h, hn);

            // ring-overwrite guard: all 8 blocks staged step s-2 (slack 2)
            const int tgt = s - 2;
            while (!__all(lane >= 8 || (int)cpre >= tgt)) {
                __builtin_amdgcn_s_sleep(1);
                if (lane < 8) cpre = ld32(&cflag[lane]);
            }
            if (!(lane & 1)) {   // packet: {epoch s+1 | 2 x f16}
                u64 v = ((u64)(u32)(s + 1) << 32) | (u64)hw;
                u64* dst = (isL1 ? ring1 + (size_t)((s - 1) & 3) * 1024
                                 : ring0 + (size_t)(s & 3) * 1024)
                           + q * 256 + w * 32 + (lane >> 1);
                st64(dst, v);
            }
        }

        // ---- stage s+1: parallel issue, ONE joint retry loop ----
        if (stg0 || stg1) {
            const int n0  = tid & 127;
            const int jj0 = tid >> 7, jj1 = 4 + jj0;
            const u64* b0 = ring0 + (size_t)((snx - 1) & 3) * 1024
                            + ((n0 >> 5) << 8) + (n0 & 31);
            const u64* a00 = b0 + jj0 * 32;
            const u64* a01 = b0 + jj1 * 32;
            u64 v00, v01, v10 = 0, v11 = 0;
            const u64 *a10 = nullptr, *a11 = nullptr;
            if (isL1) {
                const u64* b1 = ring1 + (size_t)((snx + 2) & 3) * 1024
                                + ((n0 >> 5) << 8) + (n0 & 31);
                a10 = b1 + jj0 * 32; a11 = b1 + jj1 * 32;
                v00 = ld64(a00); v01 = ld64(a01);   // 4 independent loads issue
                v10 = ld64(a10); v11 = ld64(a11);   // back-to-back (one wait)
            } else {
                v00 = ld64(a00); v01 = ld64(a01);
            }
            const u32 e0 = (u32)snx;
            const u32 e1 = (snx >= 2) ? (u32)snx : 0u;
            for (;;) {
                bool k0 = ((u32)(v00 >> 32) == e0);
                bool k1 = ((u32)(v01 >> 32) == e0);
                bool k2 = !isL1 || ((u32)(v10 >> 32) == e1);
                bool k3 = !isL1 || ((u32)(v11 >> 32) == e1);
                if (k0 & k1 & k2 & k3) break;
                if (!k0) v00 = ld64(a00);
                if (!k1) v01 = ld64(a01);
                if (isL1) {
                    if (!k2) v10 = ld64(a10);
                    if (!k3) v11 = ld64(a11);
                }
            }
            const int cb0 = isL1 ? 0 : 8;
            sBu[(cb0 + (n0 >> 2)) * 72 + jj0 * 4 + (n0 & 3)] = (u32)v00;
            sBu[(cb0 + (n0 >> 2)) * 72 + jj1 * 4 + (n0 & 3)] = (u32)v01;
            if (isL1) {
                sBu[(32 + (n0 >> 2)) * 72 + jj0 * 4 + (n0 & 3)] = (u32)v10;
                sBu[(32 + (n0 >> 2)) * 72 + jj1 * 4 + (n0 & 3)] = (u32)v11;
            }
            if (doX) {
                int t2 = tid - 256, j = t2 >> 4, c = t2 & 15;
                int bidx = (c >> 1) * 72 + j * 4 + 2 * (c & 1);
                sBu[bidx]     = pkh(xr.x, xr.y);
                sBu[bidx + 1] = pkh(xr.z, xr.w);
            }
        }
    }

    // ---- final FC on h1(TT-1): ring1 slot 3, epoch TT+1 ----
    if (isL1 && q == 0) {
        const u32 ef = (u32)(TT + 1);
        const int n0  = tid & 127;
        const int jj0 = tid >> 7, jj1 = 4 + jj0;
        const u64* b = ring1 + 3 * 1024 + ((n0 >> 5) << 8) + (n0 & 31);
        const u64* a0 = b + jj0 * 32;
        const u64* a1 = b + jj1 * 32;
        u64 v0 = ld64(a0), v1 = ld64(a1);
        for (;;) {
            bool k0 = ((u32)(v0 >> 32) == ef), k1 = ((u32)(v1 >> 32) == ef);
            if (k0 & k1) break;
            if (!k0) v0 = ld64(a0);
            if (!k1) v1 = ld64(a1);
        }
        sBu[jj0 * 128 + n0] = (u32)v0;   // flat [batch][128 u32]
        sBu[jj1 * 128 + n0] = (u32)v1;
        __syncthreads();
        const int j = tid >> 6, l2 = tid & 63;
        const int o = l2 >> 4, kk = l2 & 15;
        float ssum = 0.f;
#pragma unroll
        for (int m = 0; m < 16; ++m) {
            int k = kk * 16 + m;
            ssum += (float)sB[j * 256 + k] * fcW[o * HH + k];
        }
#pragma unroll
        for (int off = 8; off; off >>= 1) ssum += __shfl_down(ssum, off);
        if (kk == 0) out[(batch0 + j) * 4 + o] = ssum + fcb[o];
    }
}

extern "C" void kernel_launch(void* const* d_in, const int* in_sizes, int n_in,
                              void* d_out, int out_size, void* d_ws, size_t ws_size,
                              hipStream_t stream)
{
    (void)in_sizes; (void)n_in; (void)out_size; (void)ws_size;
    const float* x    = (const float*)d_in[0];
    const float* Wih0 = (const float*)d_in[1];
    const float* Whh0 = (const float*)d_in[2];
    const float* bih0 = (const float*)d_in[3];
    const float* bhh0 = (const float*)d_in[4];
    const float* Wih1 = (const float*)d_in[5];
    const float* Whh1 = (const float*)d_in[6];
    const float* bih1 = (const float*)d_in[7];
    const float* bhh1 = (const float*)d_in[8];
    const float* fcW  = (const float*)d_in[9];
    const float* fcb  = (const float*)d_in[10];
    float* out = (float*)d_out;

    // ws: h0ring 1MB (32 grp x 4 slot x 1024 u64) | h1ring 1MB | cflags 2KB
    u64* h0ring = (u64*)d_ws;
    u64* h1ring = (u64*)((char*)d_ws + 1048576);
    u32* cflags = (u32*)((char*)d_ws + 2097152);

    hipMemsetAsync(d_ws, 0, 2097152 + 2048, stream);   // epoch 0 == h(-1)=0

    lstm_persist<<<dim3(256), dim3(512), 0, stream>>>(
        x, Wih0, Whh0, bih0, bhh0, Wih1, Whh1, bih1, bhh1, fcW, fcb, out,
        h0ring, h1ring, cflags);
}